// Round 1
// baseline (72526.135 us; speedup 1.0000x reference)
//
#include <hip/hip_runtime.h>
#include <hip/hip_bf16.h>

// MogLSTM: S=512, B=64, E=H=1024, mog_iters=5.
// Persistent-kernel design: 256 blocks x 256 threads (1 block/CU), bf16 MFMA
// GEMMs with fp32 masters, device-scope barriers between dependent phases.

using bf16   = __bf16;
using bf16x4 = __attribute__((ext_vector_type(4))) __bf16;
using bf16x8 = __attribute__((ext_vector_type(8))) __bf16;
using f32x4  = __attribute__((ext_vector_type(4))) float;

#define S_LEN 512
#define BATCH 64
#define ED    1024
#define HD    1024
#define KXH   2048   // E + H
#define NG    4096   // 4H

#define MFMA16(a, b, c) __builtin_amdgcn_mfma_f32_16x16x32_bf16((a), (b), (c), 0, 0, 0)

__device__ __forceinline__ float fsig(float x)  { return 1.f / (1.f + __expf(-x)); }
__device__ __forceinline__ float ftanh(float x) { return 1.f - 2.f / (1.f + __expf(2.f * x)); }

// ---------------- device-scope barrier (generation/sense based) ----------------
__device__ __forceinline__ void bar_sync(unsigned* ctr, unsigned* gen, unsigned nblk) {
  __syncthreads();
  if (threadIdx.x == 0) {
    __threadfence();  // publish our phase's stores device-wide (wb L2)
    unsigned g = __hip_atomic_load(gen, __ATOMIC_RELAXED, __HIP_MEMORY_SCOPE_AGENT);
    unsigned a = __hip_atomic_fetch_add(ctr, 1u, __ATOMIC_ACQ_REL, __HIP_MEMORY_SCOPE_AGENT);
    if (a == nblk - 1u) {
      __hip_atomic_store(ctr, 0u, __ATOMIC_RELAXED, __HIP_MEMORY_SCOPE_AGENT);
      __hip_atomic_store(gen, g + 1u, __ATOMIC_RELEASE, __HIP_MEMORY_SCOPE_AGENT);
    } else {
      while (__hip_atomic_load(gen, __ATOMIC_RELAXED, __HIP_MEMORY_SCOPE_AGENT) == g)
        __builtin_amdgcn_s_sleep(4);
    }
    __threadfence();  // acquire (inv L2) so subsequent loads see remote writes
  }
  __syncthreads();
}

// Passive wait (no arrival) on a generation counter reaching >= target.
__device__ __forceinline__ void wait_gen(unsigned* gen, unsigned target) {
  __syncthreads();
  if (threadIdx.x == 0) {
    while (__hip_atomic_load(gen, __ATOMIC_RELAXED, __HIP_MEMORY_SCOPE_AGENT) < target)
      __builtin_amdgcn_s_sleep(16);
    __threadfence();
  }
  __syncthreads();
}

// ---------------- 64x16 GEMM tile helper, K=1024, bf16 MFMA ----------------
// abase: lane-resolved A pointer (row-major, any stride baked into pointer)
// bbase: lane-resolved W-row pointer (acts as B^T: col = W row)
__device__ __forceinline__ f32x4 gemm16(const bf16* __restrict__ abase,
                                        const bf16* __restrict__ bbase) {
  f32x4 acc = {0.f, 0.f, 0.f, 0.f};
#pragma unroll 8
  for (int k = 0; k < 1024; k += 32) {
    bf16x8 av = *(const bf16x8*)(abase + k);
    bf16x8 bv = *(const bf16x8*)(bbase + k);
    acc = MFMA16(av, bv, acc);
  }
  return acc;
}

// ---------------- prologue: convert weights to bf16, zero state ----------------
__global__ void cvt_init(const float* __restrict__ W, const float* __restrict__ Q,
                         const float* __restrict__ R,
                         bf16* __restrict__ Wb, bf16* __restrict__ Qb, bf16* __restrict__ Rb,
                         float* __restrict__ hM, float* __restrict__ cM,
                         bf16* __restrict__ xh, unsigned* __restrict__ bars) {
  const long tid = (long)blockIdx.x * blockDim.x + threadIdx.x;
  const long nth = (long)gridDim.x * blockDim.x;
  for (long i = tid; i < (long)NG * KXH / 4; i += nth) {
    float4 v = ((const float4*)W)[i];
    bf16x4 o = {(bf16)v.x, (bf16)v.y, (bf16)v.z, (bf16)v.w};
    ((bf16x4*)Wb)[i] = o;
  }
  for (long i = tid; i < (long)ED * HD / 4; i += nth) {
    float4 v = ((const float4*)Q)[i];
    bf16x4 o = {(bf16)v.x, (bf16)v.y, (bf16)v.z, (bf16)v.w};
    ((bf16x4*)Qb)[i] = o;
    float4 u = ((const float4*)R)[i];
    bf16x4 p = {(bf16)u.x, (bf16)u.y, (bf16)u.z, (bf16)u.w};
    ((bf16x4*)Rb)[i] = p;
  }
  for (long i = tid; i < (long)BATCH * HD / 4; i += nth) {
    float4 z; z.x = 0.f; z.y = 0.f; z.z = 0.f; z.w = 0.f;
    ((float4*)hM)[i] = z;
    ((float4*)cM)[i] = z;
  }
  for (long i = tid; i < (long)BATCH * KXH / 4; i += nth) {
    bf16x4 z = {(bf16)0.f, (bf16)0.f, (bf16)0.f, (bf16)0.f};
    ((bf16x4*)xh)[i] = z;
  }
  if (tid < 8) bars[tid] = 0u;
}

// ---------------- persistent kernel ----------------
__global__ __launch_bounds__(256, 1) void moglstm_kernel(
    const float* __restrict__ x_in, const float* __restrict__ b_all,
    const bf16* __restrict__ Wb, const bf16* __restrict__ Qb, const bf16* __restrict__ Rb,
    bf16* __restrict__ xh, float* __restrict__ xM, float* __restrict__ hM,
    float* __restrict__ cM, float* __restrict__ zh,
    unsigned* bars, float* __restrict__ out) {
  const int bid  = blockIdx.x;
  const int l    = threadIdx.x & 63;
  const int w    = threadIdx.x >> 6;   // wave id = M-tile
  const int r16  = l & 15;
  const int kg   = l >> 4;
  const int kb   = kg * 8;
  const int arow = w * 16 + r16;       // A-operand row for this lane
  const int rbase = w * 16 + kg * 4;   // C-fragment row base for this lane

  unsigned* c64 = bars + 0;  unsigned* g64 = bars + 1;   // 64-wide barrier
  unsigned* cfl = bars + 2;  unsigned* gfl = bars + 3;   // 256-wide barrier

  for (int t = 0; t < S_LEN; ++t) {
    if (bid < 64) {
      const int col = bid * 16 + r16;
      // ---- P1: u1 = h @ Q^T ; x1 = 2*sig(u1) * x_in[t]
      {
        f32x4 acc = gemm16(xh + (long)arow * KXH + 1024 + kb,
                           Qb + (long)(bid * 16 + r16) * 1024 + kb);
        const float* src = x_in + (long)t * (BATCH * ED);
#pragma unroll
        for (int r = 0; r < 4; ++r) {
          int row = rbase + r;
          float nv = 2.f * fsig(acc[r]) * src[row * ED + col];
          xM[row * ED + col] = nv;
          xh[(long)row * KXH + col] = (bf16)nv;
        }
      }
      bar_sync(c64, g64, 64);
      // ---- P2: v2 = x @ R^T ; h2 = 2*sig(v2) * h
      {
        f32x4 acc = gemm16(xh + (long)arow * KXH + kb,
                           Rb + (long)(bid * 16 + r16) * 1024 + kb);
#pragma unroll
        for (int r = 0; r < 4; ++r) {
          int row = rbase + r;
          float nv = 2.f * fsig(acc[r]) * hM[row * HD + col];
          hM[row * HD + col] = nv;
          xh[(long)row * KXH + 1024 + col] = (bf16)nv;
        }
      }
      bar_sync(c64, g64, 64);
      // ---- P3: u3 = h @ Q^T ; x3 = 2*sig(u3) * x1
      {
        f32x4 acc = gemm16(xh + (long)arow * KXH + 1024 + kb,
                           Qb + (long)(bid * 16 + r16) * 1024 + kb);
#pragma unroll
        for (int r = 0; r < 4; ++r) {
          int row = rbase + r;
          float nv = 2.f * fsig(acc[r]) * xM[row * ED + col];
          xM[row * ED + col] = nv;
          xh[(long)row * KXH + col] = (bf16)nv;
        }
      }
      bar_sync(c64, g64, 64);
      // ---- P4: v4 = x @ R^T ; h4 = 2*sig(v4) * h2
      {
        f32x4 acc = gemm16(xh + (long)arow * KXH + kb,
                           Rb + (long)(bid * 16 + r16) * 1024 + kb);
#pragma unroll
        for (int r = 0; r < 4; ++r) {
          int row = rbase + r;
          float nv = 2.f * fsig(acc[r]) * hM[row * HD + col];
          hM[row * HD + col] = nv;
          xh[(long)row * KXH + 1024 + col] = (bf16)nv;
        }
      }
      bar_sync(c64, g64, 64);
      // ---- P5a: u5 = h @ Q^T ; x5 = 2*sig(u5) * x3  (bf16 copy only)
      {
        f32x4 acc = gemm16(xh + (long)arow * KXH + 1024 + kb,
                           Qb + (long)(bid * 16 + r16) * 1024 + kb);
#pragma unroll
        for (int r = 0; r < 4; ++r) {
          int row = rbase + r;
          float nv = 2.f * fsig(acc[r]) * xM[row * ED + col];
          xh[(long)row * KXH + col] = (bf16)nv;
        }
      }
      // ---- P5b: zh tile (192 + bid): z_h = h4 @ Wh^T slice
      {
        const int q = 192 + bid;
        f32x4 acc = gemm16(xh + (long)arow * KXH + 1024 + kb,
                           Wb + (long)(q * 16 + r16) * KXH + 1024 + kb);
#pragma unroll
        for (int r = 0; r < 4; ++r)
          zh[(long)(rbase + r) * NG + q * 16 + r16] = acc[r];
      }
      bar_sync(cfl, gfl, 256);
      // ---- P6: z = x5 @ Wx^T + zh + b ; gates ; h,c update ; output
      {
        const bf16* ap = xh + (long)arow * KXH + kb;                      // x-half
        const bf16* b0 = Wb + (long)(bid * 16 + r16) * KXH + kb;          // i rows
        const bf16* b1 = b0 + 1024L * KXH;                                // f rows
        const bf16* b2 = b0 + 2048L * KXH;                                // g rows
        const bf16* b3 = b0 + 3072L * KXH;                                // o rows
        f32x4 ai = {0.f,0.f,0.f,0.f}, af = {0.f,0.f,0.f,0.f};
        f32x4 ag = {0.f,0.f,0.f,0.f}, ao = {0.f,0.f,0.f,0.f};
#pragma unroll 4
        for (int k = 0; k < 1024; k += 32) {
          bf16x8 av = *(const bf16x8*)(ap + k);
          ai = MFMA16(av, *(const bf16x8*)(b0 + k), ai);
          af = MFMA16(av, *(const bf16x8*)(b1 + k), af);
          ag = MFMA16(av, *(const bf16x8*)(b2 + k), ag);
          ao = MFMA16(av, *(const bf16x8*)(b3 + k), ao);
        }
        const int hcol = bid * 16 + r16;
#pragma unroll
        for (int r = 0; r < 4; ++r) {
          int row = rbase + r;
          float zi = ai[r] + zh[(long)row * NG + hcol]        + b_all[hcol];
          float zf = af[r] + zh[(long)row * NG + 1024 + hcol] + b_all[1024 + hcol];
          float zg = ag[r] + zh[(long)row * NG + 2048 + hcol] + b_all[2048 + hcol];
          float zo = ao[r] + zh[(long)row * NG + 3072 + hcol] + b_all[3072 + hcol];
          float cc = fsig(zf) * cM[row * HD + hcol] + fsig(zi) * ftanh(zg);
          float hh = fsig(zo) * ftanh(cc);
          cM[row * HD + hcol] = cc;
          hM[row * HD + hcol] = hh;
          xh[(long)row * KXH + 1024 + hcol] = (bf16)hh;
          out[(long)t * (BATCH * HD) + row * HD + hcol] = hh;
          if (t == S_LEN - 1) {
            out[(long)S_LEN * BATCH * HD + row * HD + hcol] = hh;
            out[(long)S_LEN * BATCH * HD + BATCH * HD + row * HD + hcol] = cc;
          }
        }
      }
      bar_sync(c64, g64, 64);  // h/c published for next step's P1/P2
    } else {
      // blocks 64..255: wake after P4 (g64 has advanced 5t+4 times), do one zh tile
      wait_gen(g64, 5u * (unsigned)t + 4u);
      {
        const int q = bid - 64;   // zh tiles 0..191
        f32x4 acc = gemm16(xh + (long)arow * KXH + 1024 + kb,
                           Wb + (long)(q * 16 + r16) * KXH + 1024 + kb);
#pragma unroll
        for (int r = 0; r < 4; ++r)
          zh[(long)(rbase + r) * NG + q * 16 + r16] = acc[r];
      }
      bar_sync(cfl, gfl, 256);
    }
  }
}

extern "C" void kernel_launch(void* const* d_in, const int* in_sizes, int n_in,
                              void* d_out, int out_size, void* d_ws, size_t ws_size,
                              hipStream_t stream) {
  (void)in_sizes; (void)n_in; (void)out_size; (void)ws_size;
  const float* x    = (const float*)d_in[0];
  const float* Wall = (const float*)d_in[1];
  const float* ball = (const float*)d_in[2];
  const float* Q    = (const float*)d_in[3];
  const float* R    = (const float*)d_in[4];

  char* ws = (char*)d_ws;
  size_t off = 0;
  bf16* Wb = (bf16*)(ws + off); off += (size_t)NG * KXH * 2;      // 16 MB
  bf16* Qb = (bf16*)(ws + off); off += (size_t)ED * HD * 2;       // 2 MB
  bf16* Rb = (bf16*)(ws + off); off += (size_t)HD * ED * 2;       // 2 MB
  bf16* xh = (bf16*)(ws + off); off += (size_t)BATCH * KXH * 2;   // 256 KB
  float* xM = (float*)(ws + off); off += (size_t)BATCH * ED * 4;  // 256 KB
  float* hM = (float*)(ws + off); off += (size_t)BATCH * HD * 4;  // 256 KB
  float* cM = (float*)(ws + off); off += (size_t)BATCH * HD * 4;  // 256 KB
  float* zh = (float*)(ws + off); off += (size_t)BATCH * NG * 4;  // 1 MB
  unsigned* bars = (unsigned*)(ws + off); off += 256;

  cvt_init<<<1024, 256, 0, stream>>>(Wall, Q, R, Wb, Qb, Rb, hM, cM, xh, bars);
  moglstm_kernel<<<256, 256, 0, stream>>>(x, ball, Wb, Qb, Rb, xh, xM, hM, cM, zh,
                                          bars, (float*)d_out);
}